// Round 1
// baseline (856.480 us; speedup 1.0000x reference)
//
#include <hip/hip_runtime.h>
#include <cstdint>

#define S_LEN 2048
#define HID   4096
#define NHQ   32
#define NKV   8
#define HD    128
#define QKV_N 6144

typedef float  f32x4 __attribute__((ext_vector_type(4)));
typedef short  s16x8 __attribute__((ext_vector_type(8)));
typedef unsigned short ushort_t;

typedef __attribute__((address_space(3))) void       lds_void;
typedef const __attribute__((address_space(1))) void gbl_void;

__device__ __forceinline__ void gload_lds16(const void* g, void* l) {
  __builtin_amdgcn_global_load_lds((gbl_void*)g, (lds_void*)l, 16, 0, 0);
}

__device__ __forceinline__ short f2bf_bits(float f) {
  union { __bf16 b; short s; } u;
  u.b = (__bf16)f;
  return u.s;
}
__device__ __forceinline__ float bf2f(unsigned short u) {
  union { unsigned int i; float f; } x;
  x.i = ((unsigned int)u) << 16;
  return x.f;
}

// fp32 LDS tile: 128 rows x 32 floats, stored as 16B slots with XOR swizzle:
// slot(row, cs_sw) holds source colseg cs = cs_sw ^ (row&7).
// (row stride is 128B = 32 banks; without swizzle all rows alias the same banks.)
__device__ __forceinline__ s16x8 frag_f32(const char* tile, int row, int quad) {
  const float* t = (const float*)tile;
  int cs0 = (2 * quad)     ^ (row & 7);
  int cs1 = (2 * quad + 1) ^ (row & 7);
  f32x4 a = *(const f32x4*)(t + row * 32 + cs0 * 4);
  f32x4 b = *(const f32x4*)(t + row * 32 + cs1 * 4);
  s16x8 r;
  r[0] = f2bf_bits(a[0]); r[1] = f2bf_bits(a[1]); r[2] = f2bf_bits(a[2]); r[3] = f2bf_bits(a[3]);
  r[4] = f2bf_bits(b[0]); r[5] = f2bf_bits(b[1]); r[6] = f2bf_bits(b[2]); r[7] = f2bf_bits(b[3]);
  return r;
}

// bf16 LDS tile: 128 rows x 32 bf16 row-major (64B stride -> 2-way bank alias, free).
__device__ __forceinline__ s16x8 frag_b16(const char* tile, int row, int quad) {
  return *(const s16x8*)((const ushort_t*)tile + row * 32 + quad * 8);
}

// C[M][N] = A[M][K] * B[N][K]^T  (both operands K-contiguous)
// 128x128 tile, BK=32, 4 waves each computing 64x64 via 16x16x32 bf16 MFMA.
template <bool AF32, bool BF32, bool OUTF32>
__global__ __launch_bounds__(256)
void gemm_bt(const void* __restrict__ Ap, const void* __restrict__ Bp,
             void* __restrict__ Cp, int M, int N, int K) {
  extern __shared__ char lds[];
  constexpr int ABYTES = AF32 ? 4 : 2;
  char* As = lds;
  char* Bs = lds + 128 * 32 * ABYTES;
  const int t = threadIdx.x;
  const int w = t >> 6, l = t & 63;
  const int n16 = l & 15, quad = l >> 4;
  const int m0 = blockIdx.x * 128, n0 = blockIdx.y * 128;
  const int wm = (w >> 1) * 64, wn = (w & 1) * 64;

  f32x4 acc[4][4] = {};

  for (int k0 = 0; k0 < K; k0 += 32) {
    if constexpr (AF32) {
      const float* Ag = (const float*)Ap;
#pragma unroll
      for (int c = 0; c < 4; c++) {
        int idx = (w * 4 + c) * 64 + l;           // 16B-slot id in tile
        int row = idx >> 3;
        int cs  = (idx & 7) ^ (row & 7);          // swizzled source colseg
        gload_lds16(Ag + (size_t)(m0 + row) * K + k0 + cs * 4, As + (w * 4 + c) * 1024);
      }
    } else {
      const ushort_t* Ag = (const ushort_t*)Ap;
#pragma unroll
      for (int c = 0; c < 2; c++) {
        int idx = (w * 2 + c) * 64 + l;
        int row = idx >> 2;
        int csg = idx & 3;
        gload_lds16(Ag + (size_t)(m0 + row) * K + k0 + csg * 8, As + (w * 2 + c) * 1024);
      }
    }
    if constexpr (BF32) {
      const float* Bg = (const float*)Bp;
#pragma unroll
      for (int c = 0; c < 4; c++) {
        int idx = (w * 4 + c) * 64 + l;
        int row = idx >> 3;
        int cs  = (idx & 7) ^ (row & 7);
        gload_lds16(Bg + (size_t)(n0 + row) * K + k0 + cs * 4, Bs + (w * 4 + c) * 1024);
      }
    } else {
      const ushort_t* Bg = (const ushort_t*)Bp;
#pragma unroll
      for (int c = 0; c < 2; c++) {
        int idx = (w * 2 + c) * 64 + l;
        int row = idx >> 2;
        int csg = idx & 3;
        gload_lds16(Bg + (size_t)(n0 + row) * K + k0 + csg * 8, Bs + (w * 2 + c) * 1024);
      }
    }
    __syncthreads();  // drains vmcnt(0) -> LDS tiles complete

    s16x8 afr[4], bfr[4];
#pragma unroll
    for (int i = 0; i < 4; i++) {
      if constexpr (AF32) afr[i] = frag_f32(As, wm + i * 16 + n16, quad);
      else                afr[i] = frag_b16(As, wm + i * 16 + n16, quad);
    }
#pragma unroll
    for (int j = 0; j < 4; j++) {
      if constexpr (BF32) bfr[j] = frag_f32(Bs, wn + j * 16 + n16, quad);
      else                bfr[j] = frag_b16(Bs, wn + j * 16 + n16, quad);
    }
#pragma unroll
    for (int i = 0; i < 4; i++)
#pragma unroll
      for (int j = 0; j < 4; j++)
        acc[i][j] = __builtin_amdgcn_mfma_f32_16x16x32_bf16(afr[i], bfr[j], acc[i][j], 0, 0, 0);
    __syncthreads();
  }

  // C/D layout: col = lane&15 (N from B), row = quad*4 + reg (M from A)
#pragma unroll
  for (int i = 0; i < 4; i++)
#pragma unroll
    for (int j = 0; j < 4; j++)
#pragma unroll
      for (int r = 0; r < 4; r++) {
        int row = m0 + wm + i * 16 + quad * 4 + r;
        int col = n0 + wn + j * 16 + n16;
        float v = acc[i][j][r];
        if constexpr (OUTF32) ((float*)Cp)[(size_t)row * N + col] = v;
        else ((ushort_t*)Cp)[(size_t)row * N + col] = (ushort_t)f2bf_bits(v);
      }
}

// RoPE on Q (with 1/sqrt(128) folded in) and K; scatter to [head][s][d] bf16.
__global__ __launch_bounds__(256)
void rope_scatter(const ushort_t* __restrict__ qkv, ushort_t* __restrict__ Q,
                  ushort_t* __restrict__ Kc) {
  const int s = blockIdx.x;
  const float LN1E4_64 = 0.14391156831212787f;  // ln(10000)/64
  for (int item = threadIdx.x; item < (NHQ + NKV) * 64; item += 256) {
    int head = item >> 6, i = item & 63;
    float f = expf(-(float)i * LN1E4_64);
    float ang = (float)s * f;
    float sn, cs;
    sincosf(ang, &sn, &cs);  // accurate: ang up to ~2048 rad needs real range reduction
    if (head < NHQ) {
      const ushort_t* src = qkv + (size_t)s * QKV_N + head * HD;
      float x1 = bf2f(src[i]), x2 = bf2f(src[64 + i]);
      const float sc = 0.08838834764831845f;  // 1/sqrt(128)
      ushort_t* dst = Q + ((size_t)head * S_LEN + s) * HD;
      dst[i]      = (ushort_t)f2bf_bits((x1 * cs - x2 * sn) * sc);
      dst[64 + i] = (ushort_t)f2bf_bits((x1 * sn + x2 * cs) * sc);
    } else {
      int kv = head - NHQ;
      const ushort_t* src = qkv + (size_t)s * QKV_N + 4096 + kv * HD;
      float x1 = bf2f(src[i]), x2 = bf2f(src[64 + i]);
      ushort_t* dst = Kc + ((size_t)kv * S_LEN + s) * HD;
      dst[i]      = (ushort_t)f2bf_bits(x1 * cs - x2 * sn);
      dst[64 + i] = (ushort_t)f2bf_bits(x1 * sn + x2 * cs);
    }
  }
}

// V -> Vt[kv][d][s] so PV B-fragments are 16B-contiguous.
__global__ __launch_bounds__(256)
void v_transpose(const ushort_t* __restrict__ qkv, ushort_t* __restrict__ Vt) {
  __shared__ __align__(16) ushort_t tile[64][72];
  const int s0 = blockIdx.x * 64;
  const int kv = blockIdx.y >> 1;
  const int d0 = (blockIdx.y & 1) * 64;
  const int t = threadIdx.x;
  {
    int r = t >> 2, c = (t & 3) * 16;
    const ushort_t* src = qkv + (size_t)(s0 + r) * QKV_N + 5120 + kv * HD + d0 + c;
    *(s16x8*)&tile[r][c]     = *(const s16x8*)src;
    *(s16x8*)&tile[r][c + 8] = *(const s16x8*)(src + 8);
  }
  __syncthreads();
  {
    int d = t >> 2, sseg = (t & 3) * 16;
    ushort_t* dst = Vt + ((size_t)kv * HD + d0 + d) * S_LEN + s0 + sseg;
    s16x8 o1, o2;
#pragma unroll
    for (int i = 0; i < 8; i++) { o1[i] = tile[sseg + i][d]; o2[i] = tile[sseg + 8 + i][d]; }
    *(s16x8*)dst = o1;
    *(s16x8*)(dst + 8) = o2;
  }
}

// Flash-style causal attention. Block = 1 head x 128 q-rows; 4 independent waves
// (32 rows each), NO __syncthreads: K/V fragments from global (L2), P through
// wave-private LDS. Q pre-scaled by 1/sqrt(128).
__global__ __launch_bounds__(256)
void attn_kernel(const ushort_t* __restrict__ Q, const ushort_t* __restrict__ Kc,
                 const ushort_t* __restrict__ Vt, ushort_t* __restrict__ Out) {
  __shared__ __align__(16) ushort_t Plds[4][32 * 40];  // stride 40 (80B, 16B-aligned, conflict-light)
  const int qt = blockIdx.x, h = blockIdx.y;
  const int t = threadIdx.x, w = t >> 6, l = t & 63;
  const int n16 = l & 15, quad = l >> 4;
  const int kv = h >> 2;
  const ushort_t* Qh = Q  + (size_t)h  * S_LEN * HD;
  const ushort_t* Kh = Kc + (size_t)kv * S_LEN * HD;
  const ushort_t* Vh = Vt + (size_t)kv * HD * S_LEN;
  const int q0 = qt * 128 + w * 32;

  s16x8 qf[2][4];  // A-frags: A[m=lane&15][k=quad*8+j], k-step = 32 dims
#pragma unroll
  for (int mt = 0; mt < 2; mt++)
#pragma unroll
    for (int ks = 0; ks < 4; ks++)
      qf[mt][ks] = *(const s16x8*)(Qh + (size_t)(q0 + mt * 16 + n16) * HD + ks * 32 + quad * 8);

  f32x4 o[2][8] = {};
  float mrun[2][4], lrun[2][4];
#pragma unroll
  for (int mt = 0; mt < 2; mt++)
#pragma unroll
    for (int r = 0; r < 4; r++) { mrun[mt][r] = -1e30f; lrun[mt][r] = 0.f; }

  ushort_t* P = Plds[w];
  const int ktiles = qt * 4 + w + 1;  // causal, per-wave (wave-uniform)
  for (int kt = 0; kt < ktiles; kt++) {
    const int k0 = kt * 32;
    f32x4 sacc[2][2] = {};
#pragma unroll
    for (int nt = 0; nt < 2; nt++)
#pragma unroll
      for (int ks = 0; ks < 4; ks++) {
        s16x8 kf = *(const s16x8*)(Kh + (size_t)(k0 + nt * 16 + n16) * HD + ks * 32 + quad * 8);
        sacc[0][nt] = __builtin_amdgcn_mfma_f32_16x16x32_bf16(qf[0][ks], kf, sacc[0][nt], 0, 0, 0);
        sacc[1][nt] = __builtin_amdgcn_mfma_f32_16x16x32_bf16(qf[1][ks], kf, sacc[1][nt], 0, 0, 0);
      }
    if (kt == ktiles - 1) {  // only the diagonal tile needs masking
#pragma unroll
      for (int mt = 0; mt < 2; mt++)
#pragma unroll
        for (int nt = 0; nt < 2; nt++)
#pragma unroll
          for (int r = 0; r < 4; r++) {
            int qrow = q0 + mt * 16 + quad * 4 + r;
            int key  = k0 + nt * 16 + n16;
            if (key > qrow) sacc[mt][nt][r] = -1e30f;
          }
    }
    __threadfence_block();  // order previous P reads before this tile's writes
#pragma unroll
    for (int mt = 0; mt < 2; mt++)
#pragma unroll
      for (int r = 0; r < 4; r++) {
        float tmx = fmaxf(sacc[mt][0][r], sacc[mt][1][r]);
#pragma unroll
        for (int d = 1; d < 16; d <<= 1) tmx = fmaxf(tmx, __shfl_xor(tmx, d));
        float nm = fmaxf(mrun[mt][r], tmx);
        float alpha = __expf(mrun[mt][r] - nm);
        mrun[mt][r] = nm;
        float p0 = __expf(sacc[mt][0][r] - nm);
        float p1 = __expf(sacc[mt][1][r] - nm);
        sacc[mt][0][r] = p0; sacc[mt][1][r] = p1;
        float rs = p0 + p1;
#pragma unroll
        for (int d = 1; d < 16; d <<= 1) rs += __shfl_xor(rs, d);
        lrun[mt][r] = lrun[mt][r] * alpha + rs;
#pragma unroll
        for (int nt2 = 0; nt2 < 8; nt2++) o[mt][nt2][r] *= alpha;
      }
#pragma unroll
    for (int mt = 0; mt < 2; mt++)
#pragma unroll
      for (int nt = 0; nt < 2; nt++)
#pragma unroll
        for (int r = 0; r < 4; r++)
          P[(mt * 16 + quad * 4 + r) * 40 + nt * 16 + n16] = (ushort_t)f2bf_bits(sacc[mt][nt][r]);
    __threadfence_block();  // P visible to all lanes of this wave
    s16x8 pa[2];
    pa[0] = *(const s16x8*)(P + (0 * 16 + n16) * 40 + quad * 8);
    pa[1] = *(const s16x8*)(P + (1 * 16 + n16) * 40 + quad * 8);
#pragma unroll
    for (int nt = 0; nt < 8; nt++) {
      s16x8 vf = *(const s16x8*)(Vh + (size_t)(nt * 16 + n16) * S_LEN + k0 + quad * 8);
      o[0][nt] = __builtin_amdgcn_mfma_f32_16x16x32_bf16(pa[0], vf, o[0][nt], 0, 0, 0);
      o[1][nt] = __builtin_amdgcn_mfma_f32_16x16x32_bf16(pa[1], vf, o[1][nt], 0, 0, 0);
    }
  }
#pragma unroll
  for (int mt = 0; mt < 2; mt++)
#pragma unroll
    for (int r = 0; r < 4; r++) {
      float inv = 1.0f / lrun[mt][r];
      int qrow = q0 + mt * 16 + quad * 4 + r;
#pragma unroll
      for (int nt = 0; nt < 8; nt++)
        Out[(size_t)qrow * HID + h * HD + nt * 16 + n16] = (ushort_t)f2bf_bits(o[mt][nt][r] * inv);
    }
}

extern "C" void kernel_launch(void* const* d_in, const int* in_sizes, int n_in,
                              void* d_out, int out_size, void* d_ws, size_t ws_size,
                              hipStream_t stream) {
  const float* hidden = (const float*)d_in[0];
  const float* w_qkv  = (const float*)d_in[1];
  const float* w_o    = (const float*)d_in[2];
  float* out = (float*)d_out;
  char* ws = (char*)d_ws;

  // ws layout (50.3 MB total):
  ushort_t* qkv = (ushort_t*)ws;                    // [2048][6144] bf16 (25,165,824 B)
  ushort_t* Qb  = (ushort_t*)(ws + 25165824);       // [32][2048][128]  (16,777,216 B)
  ushort_t* Kb  = (ushort_t*)(ws + 41943040);       // [8][2048][128]   ( 4,194,304 B)
  ushort_t* Vtb = (ushort_t*)(ws + 46137344);       // [8][128][2048]   ( 4,194,304 B)
  ushort_t* attn_out = (ushort_t*)ws;               // aliases qkv (dead after rope/v_t)

  gemm_bt<true, true, false><<<dim3(16, 48), 256, 32768, stream>>>(
      (const void*)hidden, (const void*)w_qkv, (void*)qkv, 2048, 6144, 4096);
  rope_scatter<<<dim3(2048), 256, 0, stream>>>(qkv, Qb, Kb);
  v_transpose<<<dim3(32, 16), 256, 0, stream>>>(qkv, Vtb);
  attn_kernel<<<dim3(16, 32), 256, 0, stream>>>(Qb, Kb, Vtb, attn_out);
  gemm_bt<false, true, true><<<dim3(16, 32), 256, 24576, stream>>>(
      (const void*)attn_out, (const void*)w_o, (void*)out, 2048, 4096, 4096);
}

// Round 2
// 662.020 us; speedup vs baseline: 1.2937x; 1.2937x over previous
//
#include <hip/hip_runtime.h>
#include <cstdint>

#define S_LEN 2048
#define HID   4096
#define NHQ   32
#define NKV   8
#define HD    128
#define QKV_N 6144

typedef float  f32x4 __attribute__((ext_vector_type(4)));
typedef short  s16x8 __attribute__((ext_vector_type(8)));
typedef unsigned short ushort_t;

typedef __attribute__((address_space(3))) void       lds_void;
typedef const __attribute__((address_space(1))) void gbl_void;

__device__ __forceinline__ void gload_lds16(const void* g, void* l) {
  __builtin_amdgcn_global_load_lds((gbl_void*)g, (lds_void*)l, 16, 0, 0);
}

__device__ __forceinline__ short f2bf_bits(float f) {
  union { __bf16 b; short s; } u;
  u.b = (__bf16)f;
  return u.s;
}
__device__ __forceinline__ float bf2f(unsigned short u) {
  union { unsigned int i; float f; } x;
  x.i = ((unsigned int)u) << 16;
  return x.f;
}

// ---------------- fp32 -> bf16 conversion (8 elems/thread) ----------------
__global__ __launch_bounds__(256)
void cvt_f32_bf16(const float* __restrict__ src, ushort_t* __restrict__ dst, int n8) {
  int i = blockIdx.x * 256 + threadIdx.x;
  if (i >= n8) return;
  const f32x4* s = (const f32x4*)src;
  f32x4 a = s[i * 2], b = s[i * 2 + 1];
  s16x8 r;
  r[0] = f2bf_bits(a[0]); r[1] = f2bf_bits(a[1]); r[2] = f2bf_bits(a[2]); r[3] = f2bf_bits(a[3]);
  r[4] = f2bf_bits(b[0]); r[5] = f2bf_bits(b[1]); r[6] = f2bf_bits(b[2]); r[7] = f2bf_bits(b[3]);
  *((s16x8*)dst + i) = r;
}

// ---------------- bf16 GEMM, C[M][N] = A[M][K] * B[N][K]^T ----------------
// m97 structure: 128x128 tile, BK=32, global_load_lds width=16, 4 waves.
__device__ __forceinline__ s16x8 frag_b16(const char* tile, int row, int quad) {
  return *(const s16x8*)((const ushort_t*)tile + row * 32 + quad * 8);
}

template <bool OUTF32>
__global__ __launch_bounds__(256)
void gemm_bt_bf16(const ushort_t* __restrict__ Ag, const ushort_t* __restrict__ Bg,
                  void* __restrict__ Cp, int M, int N, int K) {
  __shared__ __align__(16) char As[8192];
  __shared__ __align__(16) char Bs[8192];
  const int t = threadIdx.x;
  const int w = t >> 6, l = t & 63;
  const int n16 = l & 15, quad = l >> 4;
  const int m0 = blockIdx.x * 128, n0 = blockIdx.y * 128;
  const int wm = (w >> 1) * 64, wn = (w & 1) * 64;

  f32x4 acc[4][4] = {};

  for (int k0 = 0; k0 < K; k0 += 32) {
#pragma unroll
    for (int c = 0; c < 2; c++) {
      int idx = (w * 2 + c) * 64 + l;
      int row = idx >> 2, csg = idx & 3;
      gload_lds16(Ag + (size_t)(m0 + row) * K + k0 + csg * 8, As + (w * 2 + c) * 1024);
    }
#pragma unroll
    for (int c = 0; c < 2; c++) {
      int idx = (w * 2 + c) * 64 + l;
      int row = idx >> 2, csg = idx & 3;
      gload_lds16(Bg + (size_t)(n0 + row) * K + k0 + csg * 8, Bs + (w * 2 + c) * 1024);
    }
    __syncthreads();

    s16x8 afr[4], bfr[4];
#pragma unroll
    for (int i = 0; i < 4; i++) afr[i] = frag_b16(As, wm + i * 16 + n16, quad);
#pragma unroll
    for (int j = 0; j < 4; j++) bfr[j] = frag_b16(Bs, wn + j * 16 + n16, quad);
#pragma unroll
    for (int i = 0; i < 4; i++)
#pragma unroll
      for (int j = 0; j < 4; j++)
        acc[i][j] = __builtin_amdgcn_mfma_f32_16x16x32_bf16(afr[i], bfr[j], acc[i][j], 0, 0, 0);
    __syncthreads();
  }

#pragma unroll
  for (int i = 0; i < 4; i++)
#pragma unroll
    for (int j = 0; j < 4; j++)
#pragma unroll
      for (int r = 0; r < 4; r++) {
        int row = m0 + wm + i * 16 + quad * 4 + r;
        int col = n0 + wn + j * 16 + n16;
        float v = acc[i][j][r];
        if constexpr (OUTF32) ((float*)Cp)[(size_t)row * N + col] = v;
        else ((ushort_t*)Cp)[(size_t)row * N + col] = (ushort_t)f2bf_bits(v);
      }
}

// ---------------- RoPE + scatter (Q scaled by 1/sqrt(128)) ----------------
__global__ __launch_bounds__(256)
void rope_scatter(const ushort_t* __restrict__ qkv, ushort_t* __restrict__ Q,
                  ushort_t* __restrict__ Kc) {
  const int s = blockIdx.x;
  const float LN1E4_64 = 0.14391156831212787f;  // ln(10000)/64
  for (int item = threadIdx.x; item < (NHQ + NKV) * 64; item += 256) {
    int head = item >> 6, i = item & 63;
    float f = expf(-(float)i * LN1E4_64);
    float ang = (float)s * f;
    float sn, cs;
    sincosf(ang, &sn, &cs);
    if (head < NHQ) {
      const ushort_t* src = qkv + (size_t)s * QKV_N + head * HD;
      float x1 = bf2f(src[i]), x2 = bf2f(src[64 + i]);
      const float sc = 0.08838834764831845f;  // 1/sqrt(128)
      ushort_t* dst = Q + ((size_t)head * S_LEN + s) * HD;
      dst[i]      = (ushort_t)f2bf_bits((x1 * cs - x2 * sn) * sc);
      dst[64 + i] = (ushort_t)f2bf_bits((x1 * sn + x2 * cs) * sc);
    } else {
      int kv = head - NHQ;
      const ushort_t* src = qkv + (size_t)s * QKV_N + 4096 + kv * HD;
      float x1 = bf2f(src[i]), x2 = bf2f(src[64 + i]);
      ushort_t* dst = Kc + ((size_t)kv * S_LEN + s) * HD;
      dst[i]      = (ushort_t)f2bf_bits(x1 * cs - x2 * sn);
      dst[64 + i] = (ushort_t)f2bf_bits(x1 * sn + x2 * cs);
    }
  }
}

// ---------------- V -> Vt[kv][d][s] ----------------
__global__ __launch_bounds__(256)
void v_transpose(const ushort_t* __restrict__ qkv, ushort_t* __restrict__ Vt) {
  __shared__ __align__(16) ushort_t tile[64][72];
  const int s0 = blockIdx.x * 64;
  const int kv = blockIdx.y >> 1;
  const int d0 = (blockIdx.y & 1) * 64;
  const int t = threadIdx.x;
  {
    int r = t >> 2, c = (t & 3) * 16;
    const ushort_t* src = qkv + (size_t)(s0 + r) * QKV_N + 5120 + kv * HD + d0 + c;
    *(s16x8*)&tile[r][c]     = *(const s16x8*)src;
    *(s16x8*)&tile[r][c + 8] = *(const s16x8*)(src + 8);
  }
  __syncthreads();
  {
    int d = t >> 2, sseg = (t & 3) * 16;
    ushort_t* dst = Vt + ((size_t)kv * HD + d0 + d) * S_LEN + s0 + sseg;
    s16x8 o1, o2;
#pragma unroll
    for (int i = 0; i < 8; i++) { o1[i] = tile[sseg + i][d]; o2[i] = tile[sseg + 8 + i][d]; }
    *(s16x8*)dst = o1;
    *(s16x8*)(dst + 8) = o2;
  }
}

// ---------------- Flash attention: LDS-staged K/V, block-uniform trips ----------------
// Block = 1 head x 128 q-rows (4 waves x 32 rows), 64-key tiles.
// K tile [64 k][128 d], V tile [128 d][64 k], both XOR-swizzled at 16B-slot
// granularity (row strides 256B/128B would otherwise alias all rows to the
// same banks). Row-sum via ones-column MFMA (l = 9th output tile).
__global__ __launch_bounds__(256)
void attn_kernel(const ushort_t* __restrict__ Q, const ushort_t* __restrict__ Kc,
                 const ushort_t* __restrict__ Vt, ushort_t* __restrict__ Out) {
  __shared__ __align__(16) ushort_t Ks[64 * 128];      // 16 KB
  __shared__ __align__(16) ushort_t Vs[128 * 64];      // 16 KB
  __shared__ __align__(16) ushort_t Pl[4][32 * 72];    // 18 KB, per-wave P
  const int qt = 15 - blockIdx.x;                      // heavy tiles first
  const int h = blockIdx.y;
  const int t = threadIdx.x, w = t >> 6, l = t & 63;
  const int n16 = l & 15, quad = l >> 4;
  const int kv = h >> 2;
  const ushort_t* Qh = Q  + (size_t)h  * S_LEN * HD;
  const ushort_t* Kh = Kc + (size_t)kv * S_LEN * HD;
  const ushort_t* Vh = Vt + (size_t)kv * HD * S_LEN;
  const int q0 = qt * 128 + w * 32;

  s16x8 qf[2][4];
#pragma unroll
  for (int mt = 0; mt < 2; mt++)
#pragma unroll
    for (int ks = 0; ks < 4; ks++)
      qf[mt][ks] = *(const s16x8*)(Qh + (size_t)(q0 + mt * 16 + n16) * HD + ks * 32 + quad * 8);

  // ones B-frag: row n=0 of the l-column tile is all 1.0, other rows 0.
  s16x8 ones;
  {
    short v = (n16 == 0) ? (short)0x3F80 : (short)0;
#pragma unroll
    for (int j = 0; j < 8; j++) ones[j] = v;
  }

  f32x4 o[2][9] = {};
  float mrun[2][4];
#pragma unroll
  for (int mt = 0; mt < 2; mt++)
#pragma unroll
    for (int r = 0; r < 4; r++) mrun[mt][r] = -1e30f;

  ushort_t* P = Pl[w];
  const int trips = 2 * qt + 2;
  for (int kt = 0; kt < trips; kt++) {
    const int k0 = kt * 64;
    // ---- stage K tile (1024 16B slots) + V tile (1024 slots) ----
#pragma unroll
    for (int c = 0; c < 4; c++) {
      int idx = (c * 4 + w) * 64 + l;
      int row = idx >> 4, sc = idx & 15;
      int dseg = sc ^ (row & 15);
      gload_lds16(Kh + (size_t)(k0 + row) * HD + dseg * 8, (char*)Ks + (c * 4 + w) * 1024);
    }
#pragma unroll
    for (int c = 0; c < 4; c++) {
      int idx = (c * 4 + w) * 64 + l;
      int row = idx >> 3, sc = idx & 7;
      int ks2 = sc ^ (row & 7);
      gload_lds16(Vh + (size_t)row * S_LEN + k0 + ks2 * 8, (char*)Vs + (c * 4 + w) * 1024);
    }
    __syncthreads();  // tiles ready

    // ---- QK^T: sacc[2 mt][4 nt] ----
    f32x4 sacc[2][4] = {};
#pragma unroll
    for (int ks = 0; ks < 4; ks++)
#pragma unroll
      for (int nt = 0; nt < 4; nt++) {
        int row = nt * 16 + n16;
        s16x8 kf = *(const s16x8*)(Ks + row * 128 + ((ks * 4 + quad) ^ (row & 15)) * 8);
        sacc[0][nt] = __builtin_amdgcn_mfma_f32_16x16x32_bf16(qf[0][ks], kf, sacc[0][nt], 0, 0, 0);
        sacc[1][nt] = __builtin_amdgcn_mfma_f32_16x16x32_bf16(qf[1][ks], kf, sacc[1][nt], 0, 0, 0);
      }

    if (k0 + 63 > q0) {  // wave-uniform: this tile touches the diagonal (or is beyond)
#pragma unroll
      for (int mt = 0; mt < 2; mt++)
#pragma unroll
        for (int nt = 0; nt < 4; nt++)
#pragma unroll
          for (int r = 0; r < 4; r++) {
            int qrow = q0 + mt * 16 + quad * 4 + r;
            int key  = k0 + nt * 16 + n16;
            if (key > qrow) sacc[mt][nt][r] = -1e30f;
          }
    }

    // ---- online softmax (row max via 4 shuffles; row sum via ones-MFMA) ----
#pragma unroll
    for (int mt = 0; mt < 2; mt++)
#pragma unroll
      for (int r = 0; r < 4; r++) {
        float tmx = fmaxf(fmaxf(sacc[mt][0][r], sacc[mt][1][r]),
                          fmaxf(sacc[mt][2][r], sacc[mt][3][r]));
#pragma unroll
        for (int d = 1; d < 16; d <<= 1) tmx = fmaxf(tmx, __shfl_xor(tmx, d));
        float nm = fmaxf(mrun[mt][r], tmx);
        float alpha = __expf(mrun[mt][r] - nm);
        mrun[mt][r] = nm;
#pragma unroll
        for (int nt = 0; nt < 4; nt++) sacc[mt][nt][r] = __expf(sacc[mt][nt][r] - nm);
#pragma unroll
        for (int nt2 = 0; nt2 < 9; nt2++) o[mt][nt2][r] *= alpha;
      }

    // ---- P -> wave-private LDS (C-layout write, A-layout read) ----
#pragma unroll
    for (int mt = 0; mt < 2; mt++)
#pragma unroll
      for (int nt = 0; nt < 4; nt++)
#pragma unroll
        for (int r = 0; r < 4; r++)
          P[(mt * 16 + quad * 4 + r) * 72 + nt * 16 + n16] = (ushort_t)f2bf_bits(sacc[mt][nt][r]);
    asm volatile("s_waitcnt lgkmcnt(0)" ::: "memory");
    s16x8 pa[2][2];
#pragma unroll
    for (int mt = 0; mt < 2; mt++)
#pragma unroll
      for (int kseg = 0; kseg < 2; kseg++)
        pa[mt][kseg] = *(const s16x8*)(P + (mt * 16 + n16) * 72 + kseg * 32 + quad * 8);

    // ---- PV (+ ones column accumulates l into o[.][8]) ----
#pragma unroll
    for (int kseg = 0; kseg < 2; kseg++) {
#pragma unroll
      for (int ntd = 0; ntd < 8; ntd++) {
        int row = ntd * 16 + n16;
        s16x8 vf = *(const s16x8*)(Vs + row * 64 + ((kseg * 4 + quad) ^ (row & 7)) * 8);
        o[0][ntd] = __builtin_amdgcn_mfma_f32_16x16x32_bf16(pa[0][kseg], vf, o[0][ntd], 0, 0, 0);
        o[1][ntd] = __builtin_amdgcn_mfma_f32_16x16x32_bf16(pa[1][kseg], vf, o[1][ntd], 0, 0, 0);
      }
      o[0][8] = __builtin_amdgcn_mfma_f32_16x16x32_bf16(pa[0][kseg], ones, o[0][8], 0, 0, 0);
      o[1][8] = __builtin_amdgcn_mfma_f32_16x16x32_bf16(pa[1][kseg], ones, o[1][8], 0, 0, 0);
    }
    __syncthreads();  // done with K/V tiles
  }

  // ---- epilogue: divide by l (broadcast from n16==0 lane of each quad) ----
#pragma unroll
  for (int mt = 0; mt < 2; mt++)
#pragma unroll
    for (int r = 0; r < 4; r++) {
      float lsum = __shfl(o[mt][8][r], l & 48);  // lane quad*16 holds col 0
      float inv = 1.0f / lsum;
      int qrow = q0 + mt * 16 + quad * 4 + r;
#pragma unroll
      for (int ntd = 0; ntd < 8; ntd++)
        Out[(size_t)qrow * HID + h * HD + ntd * 16 + n16] = (ushort_t)f2bf_bits(o[mt][ntd][r] * inv);
    }
}

extern "C" void kernel_launch(void* const* d_in, const int* in_sizes, int n_in,
                              void* d_out, int out_size, void* d_ws, size_t ws_size,
                              hipStream_t stream) {
  const float* hidden = (const float*)d_in[0];
  const float* w_qkv  = (const float*)d_in[1];
  const float* w_o    = (const float*)d_in[2];
  float* out = (float*)d_out;
  char* ws = (char*)d_ws;

  // ws layout (96 MB peak, sequential-stream aliasing):
  ushort_t* hidden_bf = (ushort_t*)ws;                   // [2048][4096] bf16, dead after gemm1
  ushort_t* Qb        = (ushort_t*)ws;                   // aliases hidden_bf (rope runs after gemm1)
  ushort_t* wqkv_bf   = (ushort_t*)(ws + 16777216);      // [6144][4096] bf16, dead after gemm1
  ushort_t* wo_bf     = (ushort_t*)(ws + 16777216);      // aliases wqkv_bf
  ushort_t* qkv       = (ushort_t*)(ws + 67108864);      // [2048][6144] bf16, dead after rope+vt
  ushort_t* attn_out  = (ushort_t*)(ws + 67108864);      // aliases qkv
  ushort_t* Kb        = (ushort_t*)(ws + 92274688);      // [8][2048][128] bf16
  ushort_t* Vtb       = (ushort_t*)(ws + 96468992);      // [8][128][2048] bf16

  cvt_f32_bf16<<<dim3(4096),  256, 0, stream>>>(hidden, hidden_bf, 1048576);
  cvt_f32_bf16<<<dim3(12288), 256, 0, stream>>>(w_qkv,  wqkv_bf,   3145728);
  gemm_bt_bf16<false><<<dim3(16, 48), 256, 0, stream>>>(hidden_bf, wqkv_bf, (void*)qkv, 2048, 6144, 4096);
  rope_scatter<<<dim3(2048), 256, 0, stream>>>(qkv, Qb, Kb);
  v_transpose<<<dim3(32, 16), 256, 0, stream>>>(qkv, Vtb);
  cvt_f32_bf16<<<dim3(8192),  256, 0, stream>>>(w_o, wo_bf, 2097152);
  attn_kernel<<<dim3(16, 32), 256, 0, stream>>>(Qb, Kb, Vtb, attn_out);
  gemm_bt_bf16<true><<<dim3(16, 32), 256, 0, stream>>>(attn_out, wo_bf, (void*)out, 2048, 4096, 4096);
}

// Round 3
// 543.564 us; speedup vs baseline: 1.5757x; 1.2179x over previous
//
#include <hip/hip_runtime.h>
#include <cstdint>

#define S_LEN 2048
#define HID   4096
#define NHQ   32
#define NKV   8
#define HD    128
#define QKV_N 6144

typedef float  f32x4 __attribute__((ext_vector_type(4)));
typedef short  s16x8 __attribute__((ext_vector_type(8)));
typedef unsigned short ushort_t;

typedef __attribute__((address_space(3))) void       lds_void;
typedef const __attribute__((address_space(1))) void gbl_void;

__device__ __forceinline__ void gload_lds16(const void* g, void* l) {
  __builtin_amdgcn_global_load_lds((gbl_void*)g, (lds_void*)l, 16, 0, 0);
}

__device__ __forceinline__ short f2bf_bits(float f) {
  union { __bf16 b; short s; } u;
  u.b = (__bf16)f;
  return u.s;
}
__device__ __forceinline__ float bf2f(unsigned short u) {
  union { unsigned int i; float f; } x;
  x.i = ((unsigned int)u) << 16;
  return x.f;
}

// ---------------- fp32 -> bf16 conversion (8 elems/thread) ----------------
__global__ __launch_bounds__(256)
void cvt_f32_bf16(const float* __restrict__ src, ushort_t* __restrict__ dst, int n8) {
  int i = blockIdx.x * 256 + threadIdx.x;
  if (i >= n8) return;
  const f32x4* s = (const f32x4*)src;
  f32x4 a = s[i * 2], b = s[i * 2 + 1];
  s16x8 r;
  r[0] = f2bf_bits(a[0]); r[1] = f2bf_bits(a[1]); r[2] = f2bf_bits(a[2]); r[3] = f2bf_bits(a[3]);
  r[4] = f2bf_bits(b[0]); r[5] = f2bf_bits(b[1]); r[6] = f2bf_bits(b[2]); r[7] = f2bf_bits(b[3]);
  *((s16x8*)dst + i) = r;
}

// ---------------- bf16 GEMM, C[M][N] = A[M][K] * B[N][K]^T ----------------
__device__ __forceinline__ s16x8 frag_b16(const char* tile, int row, int quad) {
  return *(const s16x8*)((const ushort_t*)tile + row * 32 + quad * 8);
}

template <bool OUTF32>
__global__ __launch_bounds__(256)
void gemm_bt_bf16(const ushort_t* __restrict__ Ag, const ushort_t* __restrict__ Bg,
                  void* __restrict__ Cp, int M, int N, int K) {
  __shared__ __align__(16) char As[8192];
  __shared__ __align__(16) char Bs[8192];
  const int t = threadIdx.x;
  const int w = t >> 6, l = t & 63;
  const int n16 = l & 15, quad = l >> 4;
  const int m0 = blockIdx.x * 128, n0 = blockIdx.y * 128;
  const int wm = (w >> 1) * 64, wn = (w & 1) * 64;

  f32x4 acc[4][4] = {};

  for (int k0 = 0; k0 < K; k0 += 32) {
#pragma unroll
    for (int c = 0; c < 2; c++) {
      int idx = (w * 2 + c) * 64 + l;
      int row = idx >> 2, csg = idx & 3;
      gload_lds16(Ag + (size_t)(m0 + row) * K + k0 + csg * 8, As + (w * 2 + c) * 1024);
    }
#pragma unroll
    for (int c = 0; c < 2; c++) {
      int idx = (w * 2 + c) * 64 + l;
      int row = idx >> 2, csg = idx & 3;
      gload_lds16(Bg + (size_t)(n0 + row) * K + k0 + csg * 8, Bs + (w * 2 + c) * 1024);
    }
    __syncthreads();

    s16x8 afr[4], bfr[4];
#pragma unroll
    for (int i = 0; i < 4; i++) afr[i] = frag_b16(As, wm + i * 16 + n16, quad);
#pragma unroll
    for (int j = 0; j < 4; j++) bfr[j] = frag_b16(Bs, wn + j * 16 + n16, quad);
#pragma unroll
    for (int i = 0; i < 4; i++)
#pragma unroll
      for (int j = 0; j < 4; j++)
        acc[i][j] = __builtin_amdgcn_mfma_f32_16x16x32_bf16(afr[i], bfr[j], acc[i][j], 0, 0, 0);
    __syncthreads();
  }

#pragma unroll
  for (int i = 0; i < 4; i++)
#pragma unroll
    for (int j = 0; j < 4; j++)
#pragma unroll
      for (int r = 0; r < 4; r++) {
        int row = m0 + wm + i * 16 + quad * 4 + r;
        int col = n0 + wn + j * 16 + n16;
        float v = acc[i][j][r];
        if constexpr (OUTF32) ((float*)Cp)[(size_t)row * N + col] = v;
        else ((ushort_t*)Cp)[(size_t)row * N + col] = (ushort_t)f2bf_bits(v);
      }
}

// ---------------- RoPE + scatter (Q scaled by 1/sqrt(128)) ----------------
__global__ __launch_bounds__(256)
void rope_scatter(const ushort_t* __restrict__ qkv, ushort_t* __restrict__ Q,
                  ushort_t* __restrict__ Kc) {
  const int s = blockIdx.x;
  const float LN1E4_64 = 0.14391156831212787f;  // ln(10000)/64
  for (int item = threadIdx.x; item < (NHQ + NKV) * 64; item += 256) {
    int head = item >> 6, i = item & 63;
    float f = expf(-(float)i * LN1E4_64);
    float ang = (float)s * f;
    float sn, cs;
    sincosf(ang, &sn, &cs);
    if (head < NHQ) {
      const ushort_t* src = qkv + (size_t)s * QKV_N + head * HD;
      float x1 = bf2f(src[i]), x2 = bf2f(src[64 + i]);
      const float sc = 0.08838834764831845f;  // 1/sqrt(128)
      ushort_t* dst = Q + ((size_t)head * S_LEN + s) * HD;
      dst[i]      = (ushort_t)f2bf_bits((x1 * cs - x2 * sn) * sc);
      dst[64 + i] = (ushort_t)f2bf_bits((x1 * sn + x2 * cs) * sc);
    } else {
      int kv = head - NHQ;
      const ushort_t* src = qkv + (size_t)s * QKV_N + 4096 + kv * HD;
      float x1 = bf2f(src[i]), x2 = bf2f(src[64 + i]);
      ushort_t* dst = Kc + ((size_t)kv * S_LEN + s) * HD;
      dst[i]      = (ushort_t)f2bf_bits(x1 * cs - x2 * sn);
      dst[64 + i] = (ushort_t)f2bf_bits(x1 * sn + x2 * cs);
    }
  }
}

// ---------------- V -> Vt[kv][d][s] ----------------
__global__ __launch_bounds__(256)
void v_transpose(const ushort_t* __restrict__ qkv, ushort_t* __restrict__ Vt) {
  __shared__ __align__(16) ushort_t tile[64][72];
  const int s0 = blockIdx.x * 64;
  const int kv = blockIdx.y >> 1;
  const int d0 = (blockIdx.y & 1) * 64;
  const int t = threadIdx.x;
  {
    int r = t >> 2, c = (t & 3) * 16;
    const ushort_t* src = qkv + (size_t)(s0 + r) * QKV_N + 5120 + kv * HD + d0 + c;
    *(s16x8*)&tile[r][c]     = *(const s16x8*)src;
    *(s16x8*)&tile[r][c + 8] = *(const s16x8*)(src + 8);
  }
  __syncthreads();
  {
    int d = t >> 2, sseg = (t & 3) * 16;
    ushort_t* dst = Vt + ((size_t)kv * HD + d0 + d) * S_LEN + s0 + sseg;
    s16x8 o1, o2;
#pragma unroll
    for (int i = 0; i < 8; i++) { o1[i] = tile[sseg + i][d]; o2[i] = tile[sseg + 8 + i][d]; }
    *(s16x8*)dst = o1;
    *(s16x8*)(dst + 8) = o2;
  }
}

// ---------------- Flash attention, round 3 ----------------
// 64-row q-tiles; block bx handles the PAIR (qt=bx, qt=31-bx) -> exactly 33
// 64-key trips for every block (uniform makespan). 4 waves x 16 q-rows.
// K/V double-buffered in LDS; prefetch for trip i+1 issued right after trip
// i's single __syncthreads, so the barrier's vmcnt(0) drain hits loads that
// are ~1 trip old (global latency off the critical chain).
// Row-sum via ones-column MFMA; P via wave-private LDS.
__global__ __launch_bounds__(256)
void attn_kernel(const ushort_t* __restrict__ Q, const ushort_t* __restrict__ Kc,
                 const ushort_t* __restrict__ Vt, ushort_t* __restrict__ Out) {
  __shared__ __align__(16) ushort_t Ks[2][64 * 128];   // 32 KB
  __shared__ __align__(16) ushort_t Vs[2][128 * 64];   // 32 KB
  __shared__ __align__(16) ushort_t Pl[4][16 * 72];    // 9 KB
  const int bx = blockIdx.x;                            // 0..15
  const int h = blockIdx.y;
  const int t = threadIdx.x, w = t >> 6, l = t & 63;
  const int n16 = l & 15, quad = l >> 4;
  const int kv = h >> 2;
  const ushort_t* Qh = Q  + (size_t)h  * S_LEN * HD;
  const ushort_t* Kh = Kc + (size_t)kv * S_LEN * HD;
  const ushort_t* Vh = Vt + (size_t)kv * HD * S_LEN;

  const int qtA = bx, qtB = 31 - bx;
  const int q0A = qtA * 64 + w * 16, q0B = qtB * 64 + w * 16;
  const int tripsA = qtA + 1;                           // A trips: i = 0..bx
  const int TOTAL = 33;                                 // + B trips: 32 - bx

  s16x8 qfA[4], qfB[4];
#pragma unroll
  for (int ks = 0; ks < 4; ks++) {
    qfA[ks] = *(const s16x8*)(Qh + (size_t)(q0A + n16) * HD + ks * 32 + quad * 8);
    qfB[ks] = *(const s16x8*)(Qh + (size_t)(q0B + n16) * HD + ks * 32 + quad * 8);
  }

  s16x8 ones;
  {
    short v = (n16 == 0) ? (short)0x3F80 : (short)0;
#pragma unroll
    for (int j = 0; j < 8; j++) ones[j] = v;
  }

  f32x4 o[9] = {};
  float mrun[4] = {-1e30f, -1e30f, -1e30f, -1e30f};

  ushort_t* P = Pl[w];

  // stage K/V 64-key tile at k0 into buffer buf (2048 16B slots, 8/thread)
  auto stage = [&](int k0, int buf) {
#pragma unroll
    for (int c = 0; c < 4; c++) {
      int idx = (c * 4 + w) * 64 + l;
      int row = idx >> 4, sc = idx & 15;
      int dseg = sc ^ (row & 15);
      gload_lds16(Kh + (size_t)(k0 + row) * HD + dseg * 8,
                  (char*)&Ks[buf][0] + (c * 4 + w) * 1024);
    }
#pragma unroll
    for (int c = 0; c < 4; c++) {
      int idx = (c * 4 + w) * 64 + l;
      int row = idx >> 3, sc = idx & 7;
      int ks2 = sc ^ (row & 7);
      gload_lds16(Vh + (size_t)row * S_LEN + k0 + ks2 * 8,
                  (char*)&Vs[buf][0] + (c * 4 + w) * 1024);
    }
  };

  stage(0, 0);  // trip 0 prefetch (tile A, k0=0)

  for (int i = 0; i < TOTAL; i++) {
    const bool isA = (i < tripsA);
    const int kt = isA ? i : i - tripsA;
    const int q0 = isA ? q0A : q0B;
    const int k0 = kt * 64;
    const int buf = i & 1;

    __syncthreads();  // publishes buf; drains prefetch issued one trip ago

    if (i + 1 < TOTAL) {  // prefetch next trip into buf^1
      const bool nA = (i + 1 < tripsA);
      const int nkt = nA ? (i + 1) : (i + 1 - tripsA);
      stage(nkt * 64, buf ^ 1);
    }

    const ushort_t* KsB = &Ks[buf][0];
    const ushort_t* VsB = &Vs[buf][0];

    // ---- QK^T ----
    f32x4 sacc[4] = {};
#pragma unroll
    for (int ks = 0; ks < 4; ks++) {
      s16x8 qf = isA ? qfA[ks] : qfB[ks];
#pragma unroll
      for (int nt = 0; nt < 4; nt++) {
        int row = nt * 16 + n16;
        s16x8 kf = *(const s16x8*)(KsB + row * 128 + ((ks * 4 + quad) ^ (row & 15)) * 8);
        sacc[nt] = __builtin_amdgcn_mfma_f32_16x16x32_bf16(qf, kf, sacc[nt], 0, 0, 0);
      }
    }

    if (k0 + 63 > q0) {  // diagonal tile: causal mask
#pragma unroll
      for (int nt = 0; nt < 4; nt++)
#pragma unroll
        for (int r = 0; r < 4; r++) {
          int qrow = q0 + quad * 4 + r;
          int key  = k0 + nt * 16 + n16;
          if (key > qrow) sacc[nt][r] = -1e30f;
        }
    }

    // ---- online softmax ----
#pragma unroll
    for (int r = 0; r < 4; r++) {
      float tmx = fmaxf(fmaxf(sacc[0][r], sacc[1][r]), fmaxf(sacc[2][r], sacc[3][r]));
#pragma unroll
      for (int d = 1; d < 16; d <<= 1) tmx = fmaxf(tmx, __shfl_xor(tmx, d));
      float nm = fmaxf(mrun[r], tmx);
      float alpha = __expf(mrun[r] - nm);
      mrun[r] = nm;
#pragma unroll
      for (int nt = 0; nt < 4; nt++) sacc[nt][r] = __expf(sacc[nt][r] - nm);
#pragma unroll
      for (int nt2 = 0; nt2 < 9; nt2++) o[nt2][r] *= alpha;
    }

    // ---- P -> wave-private LDS (C-layout write, A-layout read) ----
#pragma unroll
    for (int nt = 0; nt < 4; nt++)
#pragma unroll
      for (int r = 0; r < 4; r++)
        P[(quad * 4 + r) * 72 + nt * 16 + n16] = (ushort_t)f2bf_bits(sacc[nt][r]);
    asm volatile("s_waitcnt lgkmcnt(0)" ::: "memory");
    s16x8 pa[2];
#pragma unroll
    for (int kseg = 0; kseg < 2; kseg++)
      pa[kseg] = *(const s16x8*)(P + n16 * 72 + kseg * 32 + quad * 8);

    // ---- PV (+ ones column -> row-sum in o[8]) ----
#pragma unroll
    for (int kseg = 0; kseg < 2; kseg++) {
#pragma unroll
      for (int ntd = 0; ntd < 8; ntd++) {
        int row = ntd * 16 + n16;
        s16x8 vf = *(const s16x8*)(VsB + row * 64 + ((kseg * 4 + quad) ^ (row & 7)) * 8);
        o[ntd] = __builtin_amdgcn_mfma_f32_16x16x32_bf16(pa[kseg], vf, o[ntd], 0, 0, 0);
      }
      o[8] = __builtin_amdgcn_mfma_f32_16x16x32_bf16(pa[kseg], ones, o[8], 0, 0, 0);
    }

    // ---- pass-A epilogue at the A/B boundary ----
    if (i == tripsA - 1) {
#pragma unroll
      for (int r = 0; r < 4; r++) {
        float lsum = __shfl(o[8][r], l & 48);
        float inv = 1.0f / lsum;
        int qrow = q0A + quad * 4 + r;
#pragma unroll
        for (int ntd = 0; ntd < 8; ntd++)
          Out[(size_t)qrow * HID + h * HD + ntd * 16 + n16] = (ushort_t)f2bf_bits(o[ntd][r] * inv);
      }
#pragma unroll
      for (int nt2 = 0; nt2 < 9; nt2++) o[nt2] = (f32x4){0.f, 0.f, 0.f, 0.f};
#pragma unroll
      for (int r = 0; r < 4; r++) mrun[r] = -1e30f;
    }
  }

  // ---- pass-B epilogue ----
#pragma unroll
  for (int r = 0; r < 4; r++) {
    float lsum = __shfl(o[8][r], l & 48);
    float inv = 1.0f / lsum;
    int qrow = q0B + quad * 4 + r;
#pragma unroll
    for (int ntd = 0; ntd < 8; ntd++)
      Out[(size_t)qrow * HID + h * HD + ntd * 16 + n16] = (ushort_t)f2bf_bits(o[ntd][r] * inv);
  }
}

extern "C" void kernel_launch(void* const* d_in, const int* in_sizes, int n_in,
                              void* d_out, int out_size, void* d_ws, size_t ws_size,
                              hipStream_t stream) {
  const float* hidden = (const float*)d_in[0];
  const float* w_qkv  = (const float*)d_in[1];
  const float* w_o    = (const float*)d_in[2];
  float* out = (float*)d_out;
  char* ws = (char*)d_ws;

  // ws layout (96 MB peak, sequential-stream aliasing):
  ushort_t* hidden_bf = (ushort_t*)ws;                   // [2048][4096] bf16, dead after gemm1
  ushort_t* Qb        = (ushort_t*)ws;                   // aliases hidden_bf
  ushort_t* wqkv_bf   = (ushort_t*)(ws + 16777216);      // [6144][4096] bf16, dead after gemm1
  ushort_t* wo_bf     = (ushort_t*)(ws + 16777216);      // aliases wqkv_bf
  ushort_t* qkv       = (ushort_t*)(ws + 67108864);      // [2048][6144] bf16, dead after rope+vt
  ushort_t* attn_out  = (ushort_t*)(ws + 67108864);      // aliases qkv
  ushort_t* Kb        = (ushort_t*)(ws + 92274688);      // [8][2048][128] bf16
  ushort_t* Vtb       = (ushort_t*)(ws + 96468992);      // [8][128][2048] bf16

  cvt_f32_bf16<<<dim3(4096),  256, 0, stream>>>(hidden, hidden_bf, 1048576);
  cvt_f32_bf16<<<dim3(12288), 256, 0, stream>>>(w_qkv,  wqkv_bf,   3145728);
  gemm_bt_bf16<false><<<dim3(16, 48), 256, 0, stream>>>(hidden_bf, wqkv_bf, (void*)qkv, 2048, 6144, 4096);
  rope_scatter<<<dim3(2048), 256, 0, stream>>>(qkv, Qb, Kb);
  v_transpose<<<dim3(32, 16), 256, 0, stream>>>(qkv, Vtb);
  cvt_f32_bf16<<<dim3(8192),  256, 0, stream>>>(w_o, wo_bf, 2097152);
  attn_kernel<<<dim3(16, 32), 256, 0, stream>>>(Qb, Kb, Vtb, attn_out);
  gemm_bt_bf16<true><<<dim3(16, 32), 256, 0, stream>>>(attn_out, wo_bf, (void*)out, 2048, 4096, 4096);
}

// Round 4
// 511.607 us; speedup vs baseline: 1.6741x; 1.0625x over previous
//
#include <hip/hip_runtime.h>
#include <cstdint>

#define S_LEN 2048
#define HID   4096
#define NHQ   32
#define NKV   8
#define HD    128
#define QKV_N 6144

typedef float  f32x4 __attribute__((ext_vector_type(4)));
typedef short  s16x8 __attribute__((ext_vector_type(8)));
typedef unsigned short ushort_t;

typedef __attribute__((address_space(3))) void       lds_void;
typedef const __attribute__((address_space(1))) void gbl_void;

__device__ __forceinline__ void gload_lds16(const void* g, void* l) {
  __builtin_amdgcn_global_load_lds((gbl_void*)g, (lds_void*)l, 16, 0, 0);
}

__device__ __forceinline__ short f2bf_bits(float f) {
  union { __bf16 b; short s; } u;
  u.b = (__bf16)f;
  return u.s;
}
__device__ __forceinline__ float bf2f(unsigned short u) {
  union { unsigned int i; float f; } x;
  x.i = ((unsigned int)u) << 16;
  return x.f;
}

__device__ __forceinline__ void cvt8(const float* src, ushort_t* dst, int j) {
  const f32x4* s = (const f32x4*)src;
  f32x4 a = s[j * 2], b = s[j * 2 + 1];
  s16x8 r;
  r[0] = f2bf_bits(a[0]); r[1] = f2bf_bits(a[1]); r[2] = f2bf_bits(a[2]); r[3] = f2bf_bits(a[3]);
  r[4] = f2bf_bits(b[0]); r[5] = f2bf_bits(b[1]); r[6] = f2bf_bits(b[2]); r[7] = f2bf_bits(b[3]);
  *((s16x8*)dst + j) = r;
}

// ---------------- fused cvt: hidden (1048576 vec8) + w_qkv (3145728 vec8) ----------------
__global__ __launch_bounds__(256)
void cvt_hw(const float* __restrict__ h, const float* __restrict__ wq,
            ushort_t* __restrict__ hb, ushort_t* __restrict__ wqb) {
  int i = blockIdx.x * 256 + threadIdx.x;
  if (i < 1048576) cvt8(h, hb, i);
  else             cvt8(wq, wqb, i - 1048576);
}

// ---------------- bf16 GEMM, C[M][N] = A[M][K] * B[N][K]^T ----------------
// 128x128 tile, BK=32, global_load_lds width=16, double-buffered LDS:
// stage for iter i+1 issued right after barrier i -> the barrier's vmcnt(0)
// drain hits loads that are one full compute phase old.
__device__ __forceinline__ s16x8 frag_b16(const ushort_t* tile, int row, int quad) {
  return *(const s16x8*)(tile + row * 32 + quad * 8);
}

template <bool OUTF32>
__global__ __launch_bounds__(256)
void gemm_bt_bf16(const ushort_t* __restrict__ Ag, const ushort_t* __restrict__ Bg,
                  void* __restrict__ Cp, int M, int N, int K) {
  __shared__ __align__(16) ushort_t As[2][128 * 32];
  __shared__ __align__(16) ushort_t Bs[2][128 * 32];
  const int t = threadIdx.x;
  const int w = t >> 6, l = t & 63;
  const int n16 = l & 15, quad = l >> 4;
  const int m0 = blockIdx.x * 128, n0 = blockIdx.y * 128;
  const int wm = (w >> 1) * 64, wn = (w & 1) * 64;

  // staging address components (fixed per thread)
  const int sIdx0 = (w * 2 + 0) * 64 + l;
  const int sIdx1 = (w * 2 + 1) * 64 + l;
  const int aRow0 = sIdx0 >> 2, aCs0 = (sIdx0 & 3) * 8;
  const int aRow1 = sIdx1 >> 2, aCs1 = (sIdx1 & 3) * 8;
  const ushort_t* Arow0 = Ag + (size_t)(m0 + aRow0) * K + aCs0;
  const ushort_t* Arow1 = Ag + (size_t)(m0 + aRow1) * K + aCs1;
  const ushort_t* Brow0 = Bg + (size_t)(n0 + aRow0) * K + aCs0;
  const ushort_t* Brow1 = Bg + (size_t)(n0 + aRow1) * K + aCs1;

  f32x4 acc[4][4] = {};

  auto stage = [&](int k0, int buf) {
    gload_lds16(Arow0 + k0, (char*)&As[buf][0] + (w * 2 + 0) * 1024);
    gload_lds16(Arow1 + k0, (char*)&As[buf][0] + (w * 2 + 1) * 1024);
    gload_lds16(Brow0 + k0, (char*)&Bs[buf][0] + (w * 2 + 0) * 1024);
    gload_lds16(Brow1 + k0, (char*)&Bs[buf][0] + (w * 2 + 1) * 1024);
  };
  auto compute = [&](int buf) {
    s16x8 afr[4], bfr[4];
#pragma unroll
    for (int i = 0; i < 4; i++) afr[i] = frag_b16(&As[buf][0], wm + i * 16 + n16, quad);
#pragma unroll
    for (int j = 0; j < 4; j++) bfr[j] = frag_b16(&Bs[buf][0], wn + j * 16 + n16, quad);
#pragma unroll
    for (int i = 0; i < 4; i++)
#pragma unroll
      for (int j = 0; j < 4; j++)
        acc[i][j] = __builtin_amdgcn_mfma_f32_16x16x32_bf16(afr[i], bfr[j], acc[i][j], 0, 0, 0);
  };

  const int nIter = K >> 5;  // K/32, even for K=4096
  stage(0, 0);
  for (int it = 0; it < nIter; it += 2) {
    __syncthreads();                                   // buf0 ready (staged one compute ago)
    if (it + 1 < nIter) stage((it + 1) << 5, 1);       // prefetch buf1
    compute(0);
    __syncthreads();                                   // buf1 ready
    if (it + 2 < nIter) stage((it + 2) << 5, 0);       // prefetch buf0
    compute(1);
  }

#pragma unroll
  for (int i = 0; i < 4; i++)
#pragma unroll
    for (int j = 0; j < 4; j++)
#pragma unroll
      for (int r = 0; r < 4; r++) {
        int row = m0 + wm + i * 16 + quad * 4 + r;
        int col = n0 + wn + j * 16 + n16;
        float v = acc[i][j][r];
        if constexpr (OUTF32) ((float*)Cp)[(size_t)row * N + col] = v;
        else ((ushort_t*)Cp)[(size_t)row * N + col] = (ushort_t)f2bf_bits(v);
      }
}

// ---------------- fused mid-pipeline: RoPE scatter + V-transpose + cvt(w_o) ----------------
// blocks [0,2048): rope row s; [2048,2560): v_transpose; [2560,10752): w_o cvt.
__global__ __launch_bounds__(256)
void rope_vt_cvtwo(const ushort_t* __restrict__ qkv, ushort_t* __restrict__ Q,
                   ushort_t* __restrict__ Kc, ushort_t* __restrict__ Vt,
                   const float* __restrict__ wo, ushort_t* __restrict__ wob) {
  __shared__ __align__(16) ushort_t tile[64][72];
  const int b = blockIdx.x;
  const int t = threadIdx.x;
  if (b < 2048) {
    const int s = b;
    const float LN1E4_64 = 0.14391156831212787f;  // ln(10000)/64
    for (int item = t; item < (NHQ + NKV) * 64; item += 256) {
      int head = item >> 6, i = item & 63;
      float f = expf(-(float)i * LN1E4_64);
      float ang = (float)s * f;
      float sn, cs;
      sincosf(ang, &sn, &cs);
      if (head < NHQ) {
        const ushort_t* src = qkv + (size_t)s * QKV_N + head * HD;
        float x1 = bf2f(src[i]), x2 = bf2f(src[64 + i]);
        const float sc = 0.08838834764831845f;  // 1/sqrt(128)
        ushort_t* dst = Q + ((size_t)head * S_LEN + s) * HD;
        dst[i]      = (ushort_t)f2bf_bits((x1 * cs - x2 * sn) * sc);
        dst[64 + i] = (ushort_t)f2bf_bits((x1 * sn + x2 * cs) * sc);
      } else {
        int kv = head - NHQ;
        const ushort_t* src = qkv + (size_t)s * QKV_N + 4096 + kv * HD;
        float x1 = bf2f(src[i]), x2 = bf2f(src[64 + i]);
        ushort_t* dst = Kc + ((size_t)kv * S_LEN + s) * HD;
        dst[i]      = (ushort_t)f2bf_bits(x1 * cs - x2 * sn);
        dst[64 + i] = (ushort_t)f2bf_bits(x1 * sn + x2 * cs);
      }
    }
  } else if (b < 2560) {
    const int bb = b - 2048;
    const int s0 = (bb & 31) * 64;
    const int by = bb >> 5;
    const int kv = by >> 1;
    const int d0 = (by & 1) * 64;
    {
      int r = t >> 2, c = (t & 3) * 16;
      const ushort_t* src = qkv + (size_t)(s0 + r) * QKV_N + 5120 + kv * HD + d0 + c;
      *(s16x8*)&tile[r][c]     = *(const s16x8*)src;
      *(s16x8*)&tile[r][c + 8] = *(const s16x8*)(src + 8);
    }
    __syncthreads();
    {
      int d = t >> 2, sseg = (t & 3) * 16;
      ushort_t* dst = Vt + ((size_t)kv * HD + d0 + d) * S_LEN + s0 + sseg;
      s16x8 o1, o2;
#pragma unroll
      for (int i = 0; i < 8; i++) { o1[i] = tile[sseg + i][d]; o2[i] = tile[sseg + 8 + i][d]; }
      *(s16x8*)dst = o1;
      *(s16x8*)(dst + 8) = o2;
    }
  } else {
    int j = (b - 2560) * 256 + t;  // 2097152 vec8 of w_o
    cvt8(wo, wob, j);
  }
}

// ---------------- Flash attention (round-3 structure, unchanged) ----------------
__global__ __launch_bounds__(256)
void attn_kernel(const ushort_t* __restrict__ Q, const ushort_t* __restrict__ Kc,
                 const ushort_t* __restrict__ Vt, ushort_t* __restrict__ Out) {
  __shared__ __align__(16) ushort_t Ks[2][64 * 128];   // 32 KB
  __shared__ __align__(16) ushort_t Vs[2][128 * 64];   // 32 KB
  __shared__ __align__(16) ushort_t Pl[4][16 * 72];    // 9 KB
  const int bx = blockIdx.x;                            // 0..15
  const int h = blockIdx.y;
  const int t = threadIdx.x, w = t >> 6, l = t & 63;
  const int n16 = l & 15, quad = l >> 4;
  const int kv = h >> 2;
  const ushort_t* Qh = Q  + (size_t)h  * S_LEN * HD;
  const ushort_t* Kh = Kc + (size_t)kv * S_LEN * HD;
  const ushort_t* Vh = Vt + (size_t)kv * HD * S_LEN;

  const int qtA = bx, qtB = 31 - bx;
  const int q0A = qtA * 64 + w * 16, q0B = qtB * 64 + w * 16;
  const int tripsA = qtA + 1;
  const int TOTAL = 33;

  s16x8 qfA[4], qfB[4];
#pragma unroll
  for (int ks = 0; ks < 4; ks++) {
    qfA[ks] = *(const s16x8*)(Qh + (size_t)(q0A + n16) * HD + ks * 32 + quad * 8);
    qfB[ks] = *(const s16x8*)(Qh + (size_t)(q0B + n16) * HD + ks * 32 + quad * 8);
  }

  s16x8 ones;
  {
    short v = (n16 == 0) ? (short)0x3F80 : (short)0;
#pragma unroll
    for (int j = 0; j < 8; j++) ones[j] = v;
  }

  f32x4 o[9] = {};
  float mrun[4] = {-1e30f, -1e30f, -1e30f, -1e30f};

  ushort_t* P = Pl[w];

  auto stage = [&](int k0, int buf) {
#pragma unroll
    for (int c = 0; c < 4; c++) {
      int idx = (c * 4 + w) * 64 + l;
      int row = idx >> 4, sc = idx & 15;
      int dseg = sc ^ (row & 15);
      gload_lds16(Kh + (size_t)(k0 + row) * HD + dseg * 8,
                  (char*)&Ks[buf][0] + (c * 4 + w) * 1024);
    }
#pragma unroll
    for (int c = 0; c < 4; c++) {
      int idx = (c * 4 + w) * 64 + l;
      int row = idx >> 3, sc = idx & 7;
      int ks2 = sc ^ (row & 7);
      gload_lds16(Vh + (size_t)row * S_LEN + k0 + ks2 * 8,
                  (char*)&Vs[buf][0] + (c * 4 + w) * 1024);
    }
  };

  stage(0, 0);

  for (int i = 0; i < TOTAL; i++) {
    const bool isA = (i < tripsA);
    const int kt = isA ? i : i - tripsA;
    const int q0 = isA ? q0A : q0B;
    const int k0 = kt * 64;
    const int buf = i & 1;

    __syncthreads();

    if (i + 1 < TOTAL) {
      const bool nA = (i + 1 < tripsA);
      const int nkt = nA ? (i + 1) : (i + 1 - tripsA);
      stage(nkt * 64, buf ^ 1);
    }

    const ushort_t* KsB = &Ks[buf][0];
    const ushort_t* VsB = &Vs[buf][0];

    f32x4 sacc[4] = {};
#pragma unroll
    for (int ks = 0; ks < 4; ks++) {
      s16x8 qf = isA ? qfA[ks] : qfB[ks];
#pragma unroll
      for (int nt = 0; nt < 4; nt++) {
        int row = nt * 16 + n16;
        s16x8 kf = *(const s16x8*)(KsB + row * 128 + ((ks * 4 + quad) ^ (row & 15)) * 8);
        sacc[nt] = __builtin_amdgcn_mfma_f32_16x16x32_bf16(qf, kf, sacc[nt], 0, 0, 0);
      }
    }

    if (k0 + 63 > q0) {
#pragma unroll
      for (int nt = 0; nt < 4; nt++)
#pragma unroll
        for (int r = 0; r < 4; r++) {
          int qrow = q0 + quad * 4 + r;
          int key  = k0 + nt * 16 + n16;
          if (key > qrow) sacc[nt][r] = -1e30f;
        }
    }

#pragma unroll
    for (int r = 0; r < 4; r++) {
      float tmx = fmaxf(fmaxf(sacc[0][r], sacc[1][r]), fmaxf(sacc[2][r], sacc[3][r]));
#pragma unroll
      for (int d = 1; d < 16; d <<= 1) tmx = fmaxf(tmx, __shfl_xor(tmx, d));
      float nm = fmaxf(mrun[r], tmx);
      float alpha = __expf(mrun[r] - nm);
      mrun[r] = nm;
#pragma unroll
      for (int nt = 0; nt < 4; nt++) sacc[nt][r] = __expf(sacc[nt][r] - nm);
#pragma unroll
      for (int nt2 = 0; nt2 < 9; nt2++) o[nt2][r] *= alpha;
    }

#pragma unroll
    for (int nt = 0; nt < 4; nt++)
#pragma unroll
      for (int r = 0; r < 4; r++)
        P[(quad * 4 + r) * 72 + nt * 16 + n16] = (ushort_t)f2bf_bits(sacc[nt][r]);
    asm volatile("s_waitcnt lgkmcnt(0)" ::: "memory");
    s16x8 pa[2];
#pragma unroll
    for (int kseg = 0; kseg < 2; kseg++)
      pa[kseg] = *(const s16x8*)(P + n16 * 72 + kseg * 32 + quad * 8);

#pragma unroll
    for (int kseg = 0; kseg < 2; kseg++) {
#pragma unroll
      for (int ntd = 0; ntd < 8; ntd++) {
        int row = ntd * 16 + n16;
        s16x8 vf = *(const s16x8*)(VsB + row * 64 + ((kseg * 4 + quad) ^ (row & 7)) * 8);
        o[ntd] = __builtin_amdgcn_mfma_f32_16x16x32_bf16(pa[kseg], vf, o[ntd], 0, 0, 0);
      }
      o[8] = __builtin_amdgcn_mfma_f32_16x16x32_bf16(pa[kseg], ones, o[8], 0, 0, 0);
    }

    if (i == tripsA - 1) {
#pragma unroll
      for (int r = 0; r < 4; r++) {
        float lsum = __shfl(o[8][r], l & 48);
        float inv = 1.0f / lsum;
        int qrow = q0A + quad * 4 + r;
#pragma unroll
        for (int ntd = 0; ntd < 8; ntd++)
          Out[(size_t)qrow * HID + h * HD + ntd * 16 + n16] = (ushort_t)f2bf_bits(o[ntd][r] * inv);
      }
#pragma unroll
      for (int nt2 = 0; nt2 < 9; nt2++) o[nt2] = (f32x4){0.f, 0.f, 0.f, 0.f};
#pragma unroll
      for (int r = 0; r < 4; r++) mrun[r] = -1e30f;
    }
  }

#pragma unroll
  for (int r = 0; r < 4; r++) {
    float lsum = __shfl(o[8][r], l & 48);
    float inv = 1.0f / lsum;
    int qrow = q0B + quad * 4 + r;
#pragma unroll
    for (int ntd = 0; ntd < 8; ntd++)
      Out[(size_t)qrow * HID + h * HD + ntd * 16 + n16] = (ushort_t)f2bf_bits(o[ntd][r] * inv);
  }
}

extern "C" void kernel_launch(void* const* d_in, const int* in_sizes, int n_in,
                              void* d_out, int out_size, void* d_ws, size_t ws_size,
                              hipStream_t stream) {
  const float* hidden = (const float*)d_in[0];
  const float* w_qkv  = (const float*)d_in[1];
  const float* w_o    = (const float*)d_in[2];
  float* out = (float*)d_out;
  char* ws = (char*)d_ws;

  // ws layout (96 MB peak, sequential-stream aliasing):
  ushort_t* hidden_bf = (ushort_t*)ws;                   // [2048][4096] bf16, dead after gemm1
  ushort_t* Qb        = (ushort_t*)ws;                   // aliases hidden_bf
  ushort_t* wqkv_bf   = (ushort_t*)(ws + 16777216);      // [6144][4096] bf16, dead after gemm1
  ushort_t* wo_bf     = (ushort_t*)(ws + 16777216);      // aliases wqkv_bf (written after gemm1)
  ushort_t* qkv       = (ushort_t*)(ws + 67108864);      // [2048][6144] bf16, dead after rope+vt
  ushort_t* attn_out  = (ushort_t*)(ws + 67108864);      // aliases qkv
  ushort_t* Kb        = (ushort_t*)(ws + 92274688);      // [8][2048][128] bf16
  ushort_t* Vtb       = (ushort_t*)(ws + 96468992);      // [8][128][2048] bf16

  cvt_hw<<<dim3(16384), 256, 0, stream>>>(hidden, w_qkv, hidden_bf, wqkv_bf);
  gemm_bt_bf16<false><<<dim3(16, 48), 256, 0, stream>>>(hidden_bf, wqkv_bf, (void*)qkv, 2048, 6144, 4096);
  rope_vt_cvtwo<<<dim3(10752), 256, 0, stream>>>(qkv, Qb, Kb, Vtb, w_o, wo_bf);
  attn_kernel<<<dim3(16, 32), 256, 0, stream>>>(Qb, Kb, Vtb, attn_out);
  gemm_bt_bf16<true><<<dim3(16, 32), 256, 0, stream>>>(attn_out, wo_bf, (void*)out, 2048, 4096, 4096);
}